// Round 8
// baseline (155.142 us; speedup 1.0000x reference)
//
#include <hip/hip_runtime.h>

#define NB 64      // L*B batches
#define T 1024     // t1 == t2
#define HD 128     // h

// encoded +inf for order-preserving float-as-uint atomicMin
#define EINF 0xFF800000u

typedef __attribute__((ext_vector_type(8))) short bf16x8;
typedef __attribute__((ext_vector_type(4))) float f32x4;

static __device__ __forceinline__ short f2bf(float f) {
    unsigned u = __float_as_uint(f);
    u += 0x7FFFu + ((u >> 16) & 1u);
    return (short)(u >> 16);
}
static __device__ __forceinline__ unsigned fenc(float f) {
    unsigned b = __float_as_uint(f);
    return b ^ (unsigned)(((int)b >> 31) | (int)0x80000000);
}
static __device__ __forceinline__ float fdec(unsigned u) {
    unsigned m = (~(unsigned)((int)u >> 31)) | 0x80000000u;
    return __uint_as_float(u ^ m);
}

// Phase 0: x AND y fp32 -> bf16 + exact fp32 row norms + workspace init.
// ~100 MB, pure BW (~16 us). Moving x-conversion here removes all f2bf and
// norm shuffles from wmd_main's (now 2048) prologues.
__global__ void wmd_prep(const float* __restrict__ x, const float* __restrict__ y,
                         short* __restrict__ xbf, short* __restrict__ ybf,
                         float* __restrict__ x2, float* __restrict__ y2,
                         unsigned* __restrict__ g_colmin, unsigned* __restrict__ g_rowmin,
                         float* __restrict__ sums, unsigned* __restrict__ batch_cnt,
                         unsigned* __restrict__ g_cnt) {
    int gi = blockIdx.x * 256 + threadIdx.x;          // float4 index, 2.097M total

    float4 vy = reinterpret_cast<const float4*>(y)[gi];
    short4 sy;
    sy.x = f2bf(vy.x); sy.y = f2bf(vy.y); sy.z = f2bf(vy.z); sy.w = f2bf(vy.w);
    reinterpret_cast<short4*>(ybf)[gi] = sy;
    float py = vy.x * vy.x + vy.y * vy.y + vy.z * vy.z + vy.w * vy.w;
    py += __shfl_xor(py, 1);  py += __shfl_xor(py, 2);  py += __shfl_xor(py, 4);
    py += __shfl_xor(py, 8);  py += __shfl_xor(py, 16);
    if ((threadIdx.x & 31) == 0) y2[gi >> 5] = py;

    float4 vx = reinterpret_cast<const float4*>(x)[gi];
    short4 sx;
    sx.x = f2bf(vx.x); sx.y = f2bf(vx.y); sx.z = f2bf(vx.z); sx.w = f2bf(vx.w);
    reinterpret_cast<short4*>(xbf)[gi] = sx;
    float px = vx.x * vx.x + vx.y * vx.y + vx.z * vx.z + vx.w * vx.w;
    px += __shfl_xor(px, 1);  px += __shfl_xor(px, 2);  px += __shfl_xor(px, 4);
    px += __shfl_xor(px, 8);  px += __shfl_xor(px, 16);
    if ((threadIdx.x & 31) == 0) x2[gi >> 5] = px;

    if (gi < NB * T) { g_colmin[gi] = EINF; g_rowmin[gi] = EINF; }
    if (gi < 2) sums[gi] = 0.f;
    if (gi >= 4 && gi < 4 + NB) batch_cnt[gi - 4] = 0u;
    if (gi == 4 + NB) g_cnt[0] = 0u;
}

// Phase 1: fused bf16-MFMA GEMM + min tracking + fence-free per-batch reduce.
// Round-8 structure: SINGLE-STAGE B, ZERO-BARRIER / ZERO-WAIT MAIN LOOP.
// Evidence trail: r0's 44 us is the barrier-locked family's floor (r2 depth
// neutral, r3/r4/r7 TLP never helps, r7 shows time tracks per-wave issue work
// per output). r5/r6 proved barrier-free runs clean but died on B latency.
// Fix both: block = 256 rows x 128 cols -> B panel = 32 KB, staged into LDS
// ONCE via global_load_lds (r0's proven XOR swizzle), one prologue
// __syncthreads, then 8 chunks of 16 cols with NO barriers and NO waitcnts —
// nothing is ever overwritten, so the compiler pipelines ds_reads under MFMAs
// across the whole loop. Waves own 64 rows (af[4][4]): 4 MFMA per ds_read_b128
// (2x r0, 4x r7) -> LDS reads/output halved vs r0. Prologue is pure loads
// (xbf/x2 precomputed in prep). LDS ~33.8 KB -> 4 blocks/CU; regs ~150
// natural, NO launch_bounds forcing (r1/r3/r4 lesson).
// Grid dim3(32, NB) (proven clean envelope): bx = m*8+jq, 32 blocks/batch.
__global__ __launch_bounds__(256)
void wmd_main(const short* __restrict__ xbf, const short* __restrict__ ybf,
              const float* __restrict__ x2g, const float* __restrict__ y2g,
              unsigned* __restrict__ g_colmin, unsigned* __restrict__ g_rowmin,
              float* __restrict__ sums, unsigned* __restrict__ batch_cnt,
              unsigned* __restrict__ g_cnt, float* __restrict__ out) {
    __shared__ short b_sm[128 * 128];          // 32 KB, staged once
    __shared__ float y2_sm[128];
    __shared__ unsigned col_min_sm[128];
    __shared__ unsigned last_sm;
    __shared__ float red_sm[8];

    const int tid  = threadIdx.x;
    const int m    = blockIdx.x >> 3;      // i-tile 0..3 (256 rows)
    const int jq   = blockIdx.x & 7;       // j-tile 0..7 (128 cols)
    const int n    = blockIdx.y;           // batch
    const int i0   = m * 256;
    const int j0   = jq * 128;
    const int lane = tid & 63;
    const int wave = tid >> 6;             // owns rows i0 + wave*64 .. +64
    const int l16  = lane & 15, quad = lane >> 4;
    const float FINF = __uint_as_float(0x7F800000u);

    // ---- stage the whole 128x128 B panel (32 KB): 8 x 16B DMA per wave ----
    // Linear LDS dest, XOR-swizzled global source (reader applies same XOR).
    {
        const short* ybase = ybf + (((size_t)(n * T + j0)) << 7);
        #pragma unroll
        for (int it = 0; it < 8; ++it) {
            int g   = wave * 8 + it;
            int s   = g * 64 + lane;
            int row = s >> 4;                       // 0..127
            int c   = (s & 15) ^ (row & 7);
            const short* gp = ybase + row * 128 + c * 8;
            __builtin_amdgcn_global_load_lds(
                (const __attribute__((address_space(1))) void*)gp,
                (__attribute__((address_space(3))) void*)&b_sm[g * 512],
                16, 0, 0);
        }
    }

    // ---- A fragments: pure bf16x8 loads (converted in prep) ----
    bf16x8 af[4][4];
    const short* xbase = xbf + (((size_t)(n * T + i0 + wave * 64)) << 7);
    #pragma unroll
    for (int mi = 0; mi < 4; ++mi)
        #pragma unroll
        for (int kk = 0; kk < 4; ++kk)
            af[mi][kk] = *reinterpret_cast<const bf16x8*>(
                xbase + (((size_t)(mi * 16 + l16)) << 7) + kk * 32 + quad * 8);

    // x2 for this wave's rows: 4 coalesced loads + in-wave shfl redistribution
    float x2l[4];
    #pragma unroll
    for (int mi = 0; mi < 4; ++mi)
        x2l[mi] = x2g[n * T + i0 + wave * 64 + mi * 16 + l16];
    float x2v[16];
    #pragma unroll
    for (int mi = 0; mi < 4; ++mi)
        #pragma unroll
        for (int r = 0; r < 4; ++r)
            x2v[mi * 4 + r] = __shfl(x2l[mi], quad * 4 + r);

    if (tid < 128) {
        y2_sm[tid] = y2g[n * T + j0 + tid];
        col_min_sm[tid] = EINF;
    }

    float rmin[16];
    #pragma unroll
    for (int q = 0; q < 16; ++q) rmin[q] = FINF;

    __syncthreads();    // B staged, y2_sm/col_min init visible — ONLY main barrier

    // ---- main loop: 8 chunks of 16 cols; no barriers, no waits ----
    #pragma unroll 2
    for (int c = 0; c < 8; ++c) {
        const int row = c * 16 + l16;              // this lane's B row (col j)
        float y2v = y2_sm[row];

        f32x4 acc[4];
        #pragma unroll
        for (int mi = 0; mi < 4; ++mi) {
            f32x4 z = {0.f, 0.f, 0.f, 0.f};
            acc[mi] = z;
        }

        #pragma unroll
        for (int kk = 0; kk < 4; ++kk) {
            int cc = (kk * 4 + quad) ^ (row & 7);
            bf16x8 bv = *reinterpret_cast<const bf16x8*>(&b_sm[(row * 16 + cc) * 8]);
            #pragma unroll
            for (int mi = 0; mi < 4; ++mi)
                acc[mi] = __builtin_amdgcn_mfma_f32_16x16x32_bf16(
                    af[mi][kk], bv, acc[mi], 0, 0, 0);
        }

        // ---- epilogue: fold mins (norm-add deferred where possible) ----
        float vcol = FINF;
        #pragma unroll
        for (int mi = 0; mi < 4; ++mi)
            #pragma unroll
            for (int r = 0; r < 4; ++r) {
                float xy = acc[mi][r];
                rmin[mi * 4 + r] = fminf(rmin[mi * 4 + r], fmaf(-2.f, xy, y2v));
                vcol             = fminf(vcol,             fmaf(-2.f, xy, x2v[mi * 4 + r]));
            }
        vcol = fminf(vcol, __shfl_xor(vcol, 16));  // min over wave's 64 rows
        vcol = fminf(vcol, __shfl_xor(vcol, 32));
        if (lane < 16)
            atomicMin(&col_min_sm[c * 16 + lane], fenc(vcol));   // unordered, no barrier
    }

    // ---- rows: reduce over the 128 cols, flush direct to global ----
    #pragma unroll
    for (int mi = 0; mi < 4; ++mi)
        #pragma unroll
        for (int r = 0; r < 4; ++r) {
            float v = rmin[mi * 4 + r] + x2v[mi * 4 + r];   // + x2_i
            v = fminf(v, __shfl_xor(v, 1));
            v = fminf(v, __shfl_xor(v, 2));
            v = fminf(v, __shfl_xor(v, 4));
            v = fminf(v, __shfl_xor(v, 8));
            if (l16 == 0)
                atomicMin(&g_rowmin[n * T + i0 + wave * 64 + mi * 16 + quad * 4 + r],
                          fenc(v));
        }

    __syncthreads();   // all waves' col_min atomics complete

    if (tid < 128) {
        float v = fdec(col_min_sm[tid]) + y2_sm[tid];       // + y2_j
        atomicMin(&g_colmin[n * T + j0 + tid], fenc(v));
    }

    // ---- fence-free completion protocol (32 blocks per batch) ----
    __builtin_amdgcn_s_waitcnt(0);   // this wave's atomics acked at coherent point
    __syncthreads();                 // all waves of block done
    if (tid == 0)
        last_sm = __hip_atomic_fetch_add(&batch_cnt[n], 1u, __ATOMIC_RELAXED,
                                         __HIP_MEMORY_SCOPE_AGENT);
    __syncthreads();
    if (last_sm != 31u) return;

    // last block of batch n: reduce its 1024 row/col mins (already full d^2)
    float sc = 0.f, sr = 0.f;
    for (int e = tid; e < T; e += 256) {
        unsigned cu = __hip_atomic_load(&g_colmin[n * T + e], __ATOMIC_RELAXED,
                                        __HIP_MEMORY_SCOPE_AGENT);
        unsigned ru = __hip_atomic_load(&g_rowmin[n * T + e], __ATOMIC_RELAXED,
                                        __HIP_MEMORY_SCOPE_AGENT);
        sc += sqrtf(fmaxf(fdec(cu), 0.f));
        sr += sqrtf(fmaxf(fdec(ru), 0.f));
    }
    #pragma unroll
    for (int o = 1; o < 64; o <<= 1) {
        sc += __shfl_xor(sc, o);
        sr += __shfl_xor(sr, o);
    }
    if (lane == 0) { red_sm[wave] = sc; red_sm[4 + wave] = sr; }
    __syncthreads();
    if (tid == 0) {
        atomicAdd(&sums[0], red_sm[0] + red_sm[1] + red_sm[2] + red_sm[3]);
        atomicAdd(&sums[1], red_sm[4] + red_sm[5] + red_sm[6] + red_sm[7]);
        __builtin_amdgcn_s_waitcnt(0);   // sums adds acked before counter bump
        unsigned old = __hip_atomic_fetch_add(g_cnt, 1u, __ATOMIC_RELAXED,
                                              __HIP_MEMORY_SCOPE_AGENT);
        if (old == NB - 1) {
            float a = __hip_atomic_load(&sums[0], __ATOMIC_RELAXED, __HIP_MEMORY_SCOPE_AGENT);
            float b = __hip_atomic_load(&sums[1], __ATOMIC_RELAXED, __HIP_MEMORY_SCOPE_AGENT);
            out[0] = fmaxf(a, b) * (1.0f / 67108864.0f);
        }
    }
}

extern "C" void kernel_launch(void* const* d_in, const int* in_sizes, int n_in,
                              void* d_out, int out_size, void* d_ws, size_t ws_size,
                              hipStream_t stream) {
    const float* x = (const float*)d_in[0];
    const float* y = (const float*)d_in[1];
    float* out = (float*)d_out;

    char* ws = (char*)d_ws;
    unsigned* g_colmin  = (unsigned*)(ws);                      // 256 KB
    unsigned* g_rowmin  = (unsigned*)(ws + 256 * 1024);         // 256 KB
    float*    y2g       = (float*)(ws + 512 * 1024);            // 256 KB
    float*    x2g       = (float*)(ws + 768 * 1024);            // 256 KB
    float*    sums      = (float*)(ws + 1024 * 1024);           // 2 f32
    unsigned* batch_cnt = (unsigned*)(ws + 1024 * 1024 + 256);  // 64 u32
    unsigned* g_cnt     = (unsigned*)(ws + 1024 * 1024 + 2048); // 1 u32
    short*    ybf       = (short*)(ws + 2 * 1024 * 1024);       // 16 MB
    short*    xbf       = (short*)(ws + 18 * 1024 * 1024);      // 16 MB

    wmd_prep<<<(NB * T * HD / 4) / 256, 256, 0, stream>>>(
        x, y, xbf, ybf, x2g, y2g, g_colmin, g_rowmin, sums, batch_cnt, g_cnt);
    wmd_main<<<dim3(32, NB), 256, 0, stream>>>(
        xbf, ybf, x2g, y2g, g_colmin, g_rowmin, sums, batch_cnt, g_cnt, out);
}